// Round 5
// baseline (921.350 us; speedup 1.0000x reference)
//
#include <hip/hip_runtime.h>
#include <hip/hip_bf16.h>

#define SEQ 4096
#define BSZ 2
#define NH 8
#define HD 64
#define DMODEL 512

typedef __bf16 bf16_t;
typedef __bf16 bf16x8 __attribute__((ext_vector_type(8)));
typedef __bf16 bf16x4 __attribute__((ext_vector_type(4)));
typedef float f32x4 __attribute__((ext_vector_type(4)));

__device__ __forceinline__ f32x4 mfma16(bf16x8 a, bf16x8 b, f32x4 c) {
    return __builtin_amdgcn_mfma_f32_16x16x32_bf16(a, b, c, 0, 0, 0);
}

__device__ __forceinline__ bf16x8 ld8(const bf16_t* p) {
    return *reinterpret_cast<const bf16x8*>(p);
}

__device__ __forceinline__ uint32_t pack2(bf16_t a, bf16_t b) {
    union { bf16_t h[2]; uint32_t u; } x;
    x.h[0] = a; x.h[1] = b;
    return x.u;
}

// ---------------- vectorized casts fp32 -> bf16 ----------------
__global__ void cast_x(const float* __restrict__ src, bf16_t* __restrict__ dst, int n4) {
    int i = blockIdx.x * blockDim.x + threadIdx.x;
    if (i >= n4) return;
    float4 v = reinterpret_cast<const float4*>(src)[i];
    bf16x4 o;
    o[0] = (bf16_t)v.x; o[1] = (bf16_t)v.y; o[2] = (bf16_t)v.z; o[3] = (bf16_t)v.w;
    reinterpret_cast<bf16x4*>(dst)[i] = o;
}

__global__ void cast_w(const float* __restrict__ w0, const float* __restrict__ w1,
                       const float* __restrict__ w2, const float* __restrict__ w3,
                       bf16_t* __restrict__ dst) {
    int i = blockIdx.x * blockDim.x + threadIdx.x;
    int w = i >> 16, j = i & 65535;
    const float* src = (w == 0) ? w0 : (w == 1) ? w1 : (w == 2) ? w2 : w3;
    float4 v = reinterpret_cast<const float4*>(src)[j];
    bf16x4 o;
    o[0] = (bf16_t)v.x; o[1] = (bf16_t)v.y; o[2] = (bf16_t)v.z; o[3] = (bf16_t)v.w;
    reinterpret_cast<bf16x4*>(dst)[i] = o;
}

// ---------------- GEMM1: X(8192x512) @ W^T(1536x512) -> scatter Q,K,V [b,h,s,d] ----------------
__global__ __launch_bounds__(256) void gemm_qkv(const bf16_t* __restrict__ A,
                                                const bf16_t* __restrict__ W,
                                                bf16_t* __restrict__ Qb,
                                                bf16_t* __restrict__ Kb,
                                                bf16_t* __restrict__ Vb) {
    const int K = 512;
    int lane = threadIdx.x & 63;
    int wid = threadIdx.x >> 6;
    int wm = wid & 1, wn = wid >> 1;
    int m0 = blockIdx.x * 128 + wm * 64;
    int n0 = blockIdx.y * 128 + wn * 64;
    int c = lane & 15, quad = lane >> 4;

    f32x4 acc[4][4];
#pragma unroll
    for (int i = 0; i < 4; i++)
#pragma unroll
        for (int j = 0; j < 4; j++) acc[i][j] = f32x4{0.f, 0.f, 0.f, 0.f};

    const bf16_t* Ap = A + (size_t)(m0 + c) * K + quad * 8;
    const bf16_t* Bp = W + (size_t)(n0 + c) * K + quad * 8;

#pragma unroll 2
    for (int k0 = 0; k0 < K; k0 += 32) {
        bf16x8 a[4], b[4];
#pragma unroll
        for (int t = 0; t < 4; t++) a[t] = ld8(Ap + (size_t)t * 16 * K + k0);
#pragma unroll
        for (int t = 0; t < 4; t++) b[t] = ld8(Bp + (size_t)t * 16 * K + k0);
#pragma unroll
        for (int i = 0; i < 4; i++)
#pragma unroll
            for (int j = 0; j < 4; j++) acc[i][j] = mfma16(a[i], b[j], acc[i][j]);
    }

#pragma unroll
    for (int i = 0; i < 4; i++) {
        int mbase = m0 + i * 16 + quad * 4;
#pragma unroll
        for (int j = 0; j < 4; j++) {
            int col = n0 + j * 16 + c;
            int which = col >> 9;
            int h = (col >> 6) & 7;
            int d = col & 63;
            bf16_t* dst = (which == 0) ? Qb : ((which == 1) ? Kb : Vb);
#pragma unroll
            for (int r = 0; r < 4; r++) {
                int m = mbase + r;
                int b_ = m >> 12;
                int s = m & 4095;
                dst[((size_t)(b_ * NH + h) * SEQ + s) * HD + d] = (bf16_t)acc[i][j][r];
            }
        }
    }
}

// ---------------- RoPE on Q and K in one launch ----------------
__global__ void rope2(bf16_t* __restrict__ Qb, bf16_t* __restrict__ Kb,
                      const int* __restrict__ Vp) {
    const int nh = BSZ * NH * SEQ * 32;
    int i = blockIdx.x * blockDim.x + threadIdx.x;
    if (i >= 2 * nh) return;
    int which = (i >= nh) ? 1 : 0;
    int ii = which ? i - nh : i;
    bf16_t* X = which ? Kb : Qb;
    float outscale = which ? 1.0f : 0.1803368801111204f;  // Q: 0.125*log2(e)
    int pi = ii & 31;
    int r = ii >> 5;
    int s = r & (SEQ - 1);
    int V = Vp[0];
    int f, pos;
    if (pi < 16) { f = pi;      pos = s / V; }
    else         { f = pi - 16; pos = s % V; }
    float inv = exp2f((float)f * -0.8304820237218407f);
    float ang = (float)pos * inv;
    float cs = __cosf(ang), sn = __sinf(ang);
    size_t base = (size_t)r * HD + pi * 2;
    float xe = (float)X[base];
    float xo = (float)X[base + 1];
    X[base]     = (bf16_t)((xe * cs - xo * sn) * outscale);
    X[base + 1] = (bf16_t)((xe * sn + xo * cs) * outscale);
}

// ---------------- Flash attention v5 ----------------
// 512 threads = 8 waves = 2 q-waves (64 q each) x 4 kv-quarters (1024 kv).
// Each kv-quarter pair (2 waves) shares a single-buffered 16 KB K/V LDS
// stream; 2 barriers/iter, 16 iters. 16 waves/CU (vs r4's 8) for pipe
// overlap. No max-subtraction softmax (exp2-domain, scale folded into Q).
// 4 kv-partials combined in-LDS in two rounds at the end.
__global__ __launch_bounds__(512, 4) void flash_attn(const bf16_t* __restrict__ Q,
                                                     const bf16_t* __restrict__ K,
                                                     const bf16_t* __restrict__ V,
                                                     bf16_t* __restrict__ Y) {
    // streams: kvq*16384 : K 8 KB | V^T 8 KB.  Epilogue overlays from 0.
    __shared__ __align__(16) unsigned char smem[70656];

    const int t = threadIdx.x;
    const int lane = t & 63;
    const int c = lane & 15, quad = lane >> 4;
    const int wid = t >> 6;            // 0..7
    const int w = wid & 1;             // q-wave
    const int kvq = wid >> 1;          // kv quarter
    const int bh = blockIdx.y;
    const int qw = blockIdx.x * 128 + w * 64;

    size_t base = (size_t)bh * SEQ * HD;
    const bf16_t* Qp = Q + base;
    const bf16_t* Vp = V + base + (size_t)kvq * 1024 * HD;
    const uint4* Kg = (const uint4*)(K + base) + (size_t)kvq * 1024 * 8;

    uint4* Klp = (uint4*)(smem + kvq * 16384);
    uint32_t* Vtp = (uint32_t*)(smem + kvq * 16384 + 8192);

    // Q as B-operand: lane holds Q[q = qw+qt*16+c][d = ks*32+quad*8+j]
    bf16x8 qf[4][2];
#pragma unroll
    for (int qt = 0; qt < 4; qt++)
#pragma unroll
        for (int ks = 0; ks < 2; ks++)
            qf[qt][ks] = ld8(Qp + (size_t)(qw + qt * 16 + c) * HD + ks * 32 + quad * 8);

    f32x4 acc[4][4];
#pragma unroll
    for (int qt = 0; qt < 4; qt++)
#pragma unroll
        for (int dt = 0; dt < 4; dt++) acc[qt][dt] = f32x4{0.f, 0.f, 0.f, 0.f};
    float lsum[4] = {0.f, 0.f, 0.f, 0.f};

    // staging assignments within the pair (128 threads, tp = t & 127)
    const int tp = t & 127;
    const int krow = tp >> 3;          // K: kv = i*16 + krow
    const int kblk = tp & 7;           // K 16B-block
    const int kva = 2 * (tp & 31);     // V: rows kva, kva+1
    const int dc = 16 * (tp >> 5);     // V: d base

    // prefetch tile 0 of this quarter
    uint4 kreg[4];
    bf16x8 vr0, vr1, vr2, vr3;
#pragma unroll
    for (int i = 0; i < 4; i++) kreg[i] = Kg[(size_t)(i * 16 + krow) * 8 + kblk];
    vr0 = ld8(Vp + (size_t)kva * HD + dc);
    vr1 = ld8(Vp + (size_t)(kva + 1) * HD + dc);
    vr2 = ld8(Vp + (size_t)kva * HD + dc + 8);
    vr3 = ld8(Vp + (size_t)(kva + 1) * HD + dc + 8);

    for (int kt = 0; kt < 16; kt++) {
        __syncthreads();   // all waves done READING previous tile

        // write staged regs (swizzled)
#pragma unroll
        for (int i = 0; i < 4; i++) {
            int kv = i * 16 + krow;
            int sk = (kv & 3) | (((kv >> 3) & 1) << 2);
            Klp[kv * 8 + (kblk ^ sk)] = kreg[i];
        }
#pragma unroll
        for (int j = 0; j < 8; j++) {
            int d0 = dc + j;
            int sv0 = (d0 & 7) ^ ((d0 >> 3) & 7);
            Vtp[d0 * 32 + (((kva >> 3) ^ sv0) & 7) * 4 + ((kva & 6) >> 1)] = pack2(vr0[j], vr1[j]);
            int d1 = dc + 8 + j;
            int sv1 = (d1 & 7) ^ ((d1 >> 3) & 7);
            Vtp[d1 * 32 + (((kva >> 3) ^ sv1) & 7) * 4 + ((kva & 6) >> 1)] = pack2(vr2[j], vr3[j]);
        }

        __syncthreads();   // stage visible

        // prefetch next tile (covers compute below)
        if (kt + 1 < 16) {
            int kv0n = (kt + 1) * 64;
#pragma unroll
            for (int i = 0; i < 4; i++) kreg[i] = Kg[(size_t)(kv0n + i * 16 + krow) * 8 + kblk];
            vr0 = ld8(Vp + (size_t)(kv0n + kva) * HD + dc);
            vr1 = ld8(Vp + (size_t)(kv0n + kva + 1) * HD + dc);
            vr2 = ld8(Vp + (size_t)(kv0n + kva) * HD + dc + 8);
            vr3 = ld8(Vp + (size_t)(kv0n + kva + 1) * HD + dc + 8);
        }

        // S^T = K*Q^T, kv-permuted rows; K-frags shared across 4 qt
        f32x4 st[4][4];
#pragma unroll
        for (int n = 0; n < 4; n++) {
            int kvr = (n >> 1) * 32 + ((c >> 2) * 8) + ((n & 1) * 4) + (c & 3);
            int sk = (kvr & 3) | (((kvr >> 3) & 1) << 2);
            bf16x8 k0 = *reinterpret_cast<const bf16x8*>(&Klp[kvr * 8 + (quad ^ sk)]);
            bf16x8 k1 = *reinterpret_cast<const bf16x8*>(&Klp[kvr * 8 + ((4 + quad) ^ sk)]);
#pragma unroll
            for (int qt = 0; qt < 4; qt++) {
                f32x4 z = f32x4{0.f, 0.f, 0.f, 0.f};
                z = mfma16(k0, qf[qt][0], z);
                z = mfma16(k1, qf[qt][1], z);
                st[qt][n] = z;
            }
        }

        // softmax without max-subtraction
        bf16x8 pf[4][2];
#pragma unroll
        for (int qt = 0; qt < 4; qt++) {
            float e[4][4];
            float ls = 0.f;
#pragma unroll
            for (int n = 0; n < 4; n++)
#pragma unroll
                for (int r = 0; r < 4; r++) {
                    float v = __builtin_amdgcn_exp2f(st[qt][n][r]);
                    e[n][r] = v;
                    ls += v;
                }
            lsum[qt] += ls;
            bf16x8 f0, f1;
#pragma unroll
            for (int j = 0; j < 8; j++) {
                f0[j] = (bf16_t)e[(j >> 2)][j & 3];
                f1[j] = (bf16_t)e[2 + (j >> 2)][j & 3];
            }
            pf[qt][0] = f0;
            pf[qt][1] = f1;
        }

        // O^T += V^T * P^T ; V-frags shared across 4 qt
#pragma unroll
        for (int dt = 0; dt < 4; dt++) {
            int d = dt * 16 + c;
            int sv = (d & 7) ^ ((d >> 3) & 7);
            bf16x8 v0f = *reinterpret_cast<const bf16x8*>(&Vtp[d * 32 + ((quad ^ sv) & 7) * 4]);
            bf16x8 v1f = *reinterpret_cast<const bf16x8*>(&Vtp[d * 32 + (((4 + quad) ^ sv) & 7) * 4]);
#pragma unroll
            for (int qt = 0; qt < 4; qt++) {
                acc[qt][dt] = mfma16(v0f, pf[qt][0], acc[qt][dt]);
                acc[qt][dt] = mfma16(v1f, pf[qt][1], acc[qt][dt]);
            }
        }
    }

    // reduce l across quads (each lane ends with row total for its q=c rows)
    float lred[4];
#pragma unroll
    for (int qt = 0; qt < 4; qt++) {
        float lt = lsum[qt];
        lt += __shfl_xor(lt, 16, 64);
        lt += __shfl_xor(lt, 32, 64);
        lred[qt] = lt;
    }

    // ---- combine 4 kv-partials in LDS, two rounds ----
    // O regions: id*4352 floats, row stride 68 (bank-spread); Lx after.
    float* Obuf = (float*)smem;
    float* Lx = (float*)(smem + 69632);

    __syncthreads();
    if (kvq >= 2) {       // round A dump: ids 0..3 = (kvq-2)*2 + w
        int id = (kvq - 2) * 2 + w;
#pragma unroll
        for (int qt = 0; qt < 4; qt++) {
            int row = qt * 16 + c;
#pragma unroll
            for (int dt = 0; dt < 4; dt++)
                *reinterpret_cast<f32x4*>(&Obuf[id * 4352 + row * 68 + dt * 16 + quad * 4]) = acc[qt][dt];
            if (quad == 0) Lx[id * 64 + row] = lred[qt];
        }
    }
    __syncthreads();
    if (kvq < 2) {        // round A add: kvq0 += (kvq2), kvq1 += (kvq3)
        int id = kvq * 2 + w;
#pragma unroll
        for (int qt = 0; qt < 4; qt++) {
            int row = qt * 16 + c;
#pragma unroll
            for (int dt = 0; dt < 4; dt++)
                acc[qt][dt] += *reinterpret_cast<const f32x4*>(&Obuf[id * 4352 + row * 68 + dt * 16 + quad * 4]);
            lred[qt] += Lx[id * 64 + row];
        }
    }
    __syncthreads();
    if (kvq == 1) {       // round B dump: id = w
#pragma unroll
        for (int qt = 0; qt < 4; qt++) {
            int row = qt * 16 + c;
#pragma unroll
            for (int dt = 0; dt < 4; dt++)
                *reinterpret_cast<f32x4*>(&Obuf[w * 4352 + row * 68 + dt * 16 + quad * 4]) = acc[qt][dt];
            if (quad == 0) Lx[w * 64 + row] = lred[qt];
        }
    }
    __syncthreads();
    if (kvq == 0) {       // round B add + normalize + write
        int b_ = bh >> 3, h = bh & 7;
#pragma unroll
        for (int qt = 0; qt < 4; qt++) {
            int row = qt * 16 + c;
#pragma unroll
            for (int dt = 0; dt < 4; dt++)
                acc[qt][dt] += *reinterpret_cast<const f32x4*>(&Obuf[w * 4352 + row * 68 + dt * 16 + quad * 4]);
            float inv_l = 1.0f / (lred[qt] + Lx[w * 64 + row]);
            int srow = qw + qt * 16 + c;
            bf16_t* yrow = Y + (size_t)(b_ * SEQ + srow) * DMODEL + h * HD;
#pragma unroll
            for (int dt = 0; dt < 4; dt++) {
                bf16x4 o;
#pragma unroll
                for (int r = 0; r < 4; r++) o[r] = (bf16_t)(acc[qt][dt][r] * inv_l);
                *reinterpret_cast<bf16x4*>(yrow + dt * 16 + quad * 4) = o;
            }
        }
    }
}

// ---------------- GEMM2: Y(8192x512) @ Wo^T(512x512) -> out fp32 ----------------
__global__ __launch_bounds__(256) void gemm_out(const bf16_t* __restrict__ A,
                                                const bf16_t* __restrict__ W,
                                                float* __restrict__ out) {
    const int K = 512;
    int lane = threadIdx.x & 63;
    int wid = threadIdx.x >> 6;
    int wm = wid & 1, wn = wid >> 1;
    int m0 = blockIdx.x * 128 + wm * 64;
    int n0 = blockIdx.y * 128 + wn * 64;
    int c = lane & 15, quad = lane >> 4;

    f32x4 acc[4][4];
#pragma unroll
    for (int i = 0; i < 4; i++)
#pragma unroll
        for (int j = 0; j < 4; j++) acc[i][j] = f32x4{0.f, 0.f, 0.f, 0.f};

    const bf16_t* Ap = A + (size_t)(m0 + c) * K + quad * 8;
    const bf16_t* Bp = W + (size_t)(n0 + c) * K + quad * 8;

#pragma unroll 2
    for (int k0 = 0; k0 < K; k0 += 32) {
        bf16x8 a[4], b[4];
#pragma unroll
        for (int t = 0; t < 4; t++) a[t] = ld8(Ap + (size_t)t * 16 * K + k0);
#pragma unroll
        for (int t = 0; t < 4; t++) b[t] = ld8(Bp + (size_t)t * 16 * K + k0);
#pragma unroll
        for (int i = 0; i < 4; i++)
#pragma unroll
            for (int j = 0; j < 4; j++) acc[i][j] = mfma16(a[i], b[j], acc[i][j]);
    }

#pragma unroll
    for (int i = 0; i < 4; i++) {
        int mbase = m0 + i * 16 + quad * 4;
#pragma unroll
        for (int j = 0; j < 4; j++) {
            int col = n0 + j * 16 + c;
#pragma unroll
            for (int r = 0; r < 4; r++) {
                out[(size_t)(mbase + r) * DMODEL + col] = acc[i][j][r];
            }
        }
    }
}

extern "C" void kernel_launch(void* const* d_in, const int* in_sizes, int n_in,
                              void* d_out, int out_size, void* d_ws, size_t ws_size,
                              hipStream_t stream) {
    (void)in_sizes; (void)n_in; (void)out_size; (void)ws_size;
    const float* x  = (const float*)d_in[0];
    const float* Wq = (const float*)d_in[1];
    const float* Wk = (const float*)d_in[2];
    const float* Wv = (const float*)d_in[3];
    const float* Wo = (const float*)d_in[4];
    const int*   Vp = (const int*)d_in[6];
    float* out = (float*)d_out;

    bf16_t* ws  = (bf16_t*)d_ws;
    bf16_t* Xb  = ws;                    // 8192*512
    bf16_t* Wc  = Xb  + 4194304;         // [Wq|Wk|Wv]
    bf16_t* Wob = Wc  + 786432;          // 512*512
    bf16_t* Qb  = Wob + 262144;
    bf16_t* Kb  = Qb  + 4194304;
    bf16_t* Vb  = Kb  + 4194304;
    bf16_t* Yb  = Vb  + 4194304;

    cast_x<<<4096, 256, 0, stream>>>(x, Xb, 1048576);
    cast_w<<<1024, 256, 0, stream>>>(Wq, Wk, Wv, Wo, Wc);

    gemm_qkv<<<dim3(64, 12), 256, 0, stream>>>(Xb, Wc, Qb, Kb, Vb);

    rope2<<<16384, 256, 0, stream>>>(Qb, Kb, Vp);

    flash_attn<<<dim3(32, 16), 512, 0, stream>>>(Qb, Kb, Vb, Yb);

    gemm_out<<<dim3(64, 4), 256, 0, stream>>>(Yb, Wob, out);
}

// Round 6
// 253.034 us; speedup vs baseline: 3.6412x; 3.6412x over previous
//
#include <hip/hip_runtime.h>
#include <hip/hip_bf16.h>

#define SEQ 4096
#define BSZ 2
#define NH 8
#define HD 64
#define DMODEL 512

typedef __bf16 bf16_t;
typedef __bf16 bf16x8 __attribute__((ext_vector_type(8)));
typedef __bf16 bf16x4 __attribute__((ext_vector_type(4)));
typedef float f32x4 __attribute__((ext_vector_type(4)));

__device__ __forceinline__ f32x4 mfma16(bf16x8 a, bf16x8 b, f32x4 c) {
    return __builtin_amdgcn_mfma_f32_16x16x32_bf16(a, b, c, 0, 0, 0);
}

__device__ __forceinline__ bf16x8 ld8(const bf16_t* p) {
    return *reinterpret_cast<const bf16x8*>(p);
}

__device__ __forceinline__ uint32_t pack2(bf16_t a, bf16_t b) {
    union { bf16_t h[2]; uint32_t u; } x;
    x.h[0] = a; x.h[1] = b;
    return x.u;
}

// async global->LDS DMA, 16 B/lane; lds dest must be wave-uniform base
// (data lands at base + lane*16)
__device__ __forceinline__ void gl_lds16(const bf16_t* g, bf16_t* l) {
    __builtin_amdgcn_global_load_lds(
        (const __attribute__((address_space(1))) uint32_t*)g,
        (__attribute__((address_space(3))) uint32_t*)l,
        16, 0, 0);
}

// ---------------- fused cast fp32 -> bf16 (x + all 4 weights) ----------------
__global__ void cast_all(const float* __restrict__ x,
                         const float* __restrict__ wq, const float* __restrict__ wk,
                         const float* __restrict__ wv, const float* __restrict__ wo,
                         bf16_t* __restrict__ Xb, bf16_t* __restrict__ Wc,
                         bf16_t* __restrict__ Wob) {
    int i = blockIdx.x * blockDim.x + threadIdx.x;   // float4-group index
    const float* src;
    bf16_t* dst;
    int j;
    if (i < 1048576) { src = x; dst = Xb; j = i; }
    else {
        int k = i - 1048576;
        int w = k >> 16;
        j = k & 65535;
        src = (w == 0) ? wq : (w == 1) ? wk : (w == 2) ? wv : wo;
        dst = (w == 3) ? Wob : Wc + w * 262144;
    }
    float4 v = reinterpret_cast<const float4*>(src)[j];
    bf16x4 o;
    o[0] = (bf16_t)v.x; o[1] = (bf16_t)v.y; o[2] = (bf16_t)v.z; o[3] = (bf16_t)v.w;
    reinterpret_cast<bf16x4*>(dst)[j] = o;
}

// ---------------- m97-style GEMM core: out[m][n] = sum_k A[m][k] B[n][k] ----------------
// 128x128 block tile, 4 waves (2x2, 64x64 each), BK=32, single-buffered LDS,
// global_load_lds width-16 staging, ds_read_b128 frags.
__device__ __forceinline__ void gemm_core_128(const bf16_t* __restrict__ A,
                                              const bf16_t* __restrict__ B,
                                              int m0, int n0,
                                              bf16_t* As, bf16_t* Bs,   // [128*32] each
                                              f32x4 acc[4][4]) {
    const int t = threadIdx.x;
    const int lane = t & 63;
    const int wid = t >> 6;
    const int c = lane & 15, quad = lane >> 4;
    const int wm = wid & 1, wn = wid >> 1;

#pragma unroll
    for (int i = 0; i < 4; i++)
#pragma unroll
        for (int j = 0; j < 4; j++) acc[i][j] = f32x4{0.f, 0.f, 0.f, 0.f};

    // staging map: wave wid covers rows [wid*32, wid*32+32) of both tiles.
    // instr lane l -> row = base + l/4, 16B-chunk = l%4  (LDS row-major [row][32k])
    const int lrow = lane >> 2;
    const int lch = lane & 3;
    const bf16_t* Ag = A + (size_t)(m0 + wid * 32 + lrow) * 512 + lch * 8;
    const bf16_t* Bg = B + (size_t)(n0 + wid * 32 + lrow) * 512 + lch * 8;
    bf16_t* Asw0 = As + (wid * 32) * 32;
    bf16_t* Asw1 = As + (wid * 32 + 16) * 32;
    bf16_t* Bsw0 = Bs + (wid * 32) * 32;
    bf16_t* Bsw1 = Bs + (wid * 32 + 16) * 32;

    for (int k0 = 0; k0 < 512; k0 += 32) {
        gl_lds16(Ag + k0, Asw0);
        gl_lds16(Ag + 16 * 512 + k0, Asw1);
        gl_lds16(Bg + k0, Bsw0);
        gl_lds16(Bg + 16 * 512 + k0, Bsw1);
        __syncthreads();   // drains DMA (vmcnt 0) + arrival

        bf16x8 a[4], b[4];
#pragma unroll
        for (int i = 0; i < 4; i++) a[i] = ld8(&As[(wm * 64 + i * 16 + c) * 32 + quad * 8]);
#pragma unroll
        for (int j = 0; j < 4; j++) b[j] = ld8(&Bs[(wn * 64 + j * 16 + c) * 32 + quad * 8]);
#pragma unroll
        for (int i = 0; i < 4; i++)
#pragma unroll
            for (int j = 0; j < 4; j++) acc[i][j] = mfma16(a[i], b[j], acc[i][j]);

        __syncthreads();   // all reads done before next DMA overwrites
    }
}

// ---------------- GEMM1: X(8192x512) @ W^T(1536x512) -> scatter Q,K,V [b,h,s,d] ----------------
__global__ __launch_bounds__(256) void gemm_qkv(const bf16_t* __restrict__ A,
                                                const bf16_t* __restrict__ W,
                                                bf16_t* __restrict__ Qb,
                                                bf16_t* __restrict__ Kb,
                                                bf16_t* __restrict__ Vb) {
    __shared__ bf16_t As[128 * 32];
    __shared__ bf16_t Bs[128 * 32];
    const int lane = threadIdx.x & 63;
    const int wid = threadIdx.x >> 6;
    const int c = lane & 15, quad = lane >> 4;
    const int wm = wid & 1, wn = wid >> 1;
    const int m0 = blockIdx.x * 128;
    const int n0 = blockIdx.y * 128;

    f32x4 acc[4][4];
    gemm_core_128(A, W, m0, n0, As, Bs, acc);

    // scatter epilogue: col -> (which, h, d); row -> (b, s)
#pragma unroll
    for (int i = 0; i < 4; i++) {
        int mbase = m0 + wm * 64 + i * 16 + quad * 4;
#pragma unroll
        for (int j = 0; j < 4; j++) {
            int col = n0 + wn * 64 + j * 16 + c;
            int which = col >> 9;
            int h = (col >> 6) & 7;
            int d = col & 63;
            bf16_t* dst = (which == 0) ? Qb : ((which == 1) ? Kb : Vb);
#pragma unroll
            for (int r = 0; r < 4; r++) {
                int m = mbase + r;
                int b_ = m >> 12;
                int s = m & 4095;
                dst[((size_t)(b_ * NH + h) * SEQ + s) * HD + d] = (bf16_t)acc[i][j][r];
            }
        }
    }
}

// ---------------- GEMM2: Y(8192x512) @ Wo^T(512x512) -> out fp32 ----------------
__global__ __launch_bounds__(256) void gemm_out(const bf16_t* __restrict__ A,
                                                const bf16_t* __restrict__ W,
                                                float* __restrict__ out) {
    __shared__ bf16_t As[128 * 32];
    __shared__ bf16_t Bs[128 * 32];
    const int lane = threadIdx.x & 63;
    const int wid = threadIdx.x >> 6;
    const int c = lane & 15, quad = lane >> 4;
    const int wm = wid & 1, wn = wid >> 1;
    const int m0 = blockIdx.x * 128;
    const int n0 = blockIdx.y * 128;

    f32x4 acc[4][4];
    gemm_core_128(A, W, m0, n0, As, Bs, acc);

#pragma unroll
    for (int i = 0; i < 4; i++) {
        int mbase = m0 + wm * 64 + i * 16 + quad * 4;
#pragma unroll
        for (int j = 0; j < 4; j++) {
            int col = n0 + wn * 64 + j * 16 + c;
#pragma unroll
            for (int r = 0; r < 4; r++)
                out[(size_t)(mbase + r) * DMODEL + col] = acc[i][j][r];
        }
    }
}

// ---------------- RoPE on Q and K in one launch ----------------
__global__ void rope2(bf16_t* __restrict__ Qb, bf16_t* __restrict__ Kb,
                      const int* __restrict__ Vp) {
    const int nh = BSZ * NH * SEQ * 32;
    int i = blockIdx.x * blockDim.x + threadIdx.x;
    if (i >= 2 * nh) return;
    int which = (i >= nh) ? 1 : 0;
    int ii = which ? i - nh : i;
    bf16_t* X = which ? Kb : Qb;
    float outscale = which ? 1.0f : 0.1803368801111204f;  // Q: 0.125*log2(e)
    int pi = ii & 31;
    int r = ii >> 5;
    int s = r & (SEQ - 1);
    int V = Vp[0];
    int f, pos;
    if (pi < 16) { f = pi;      pos = s / V; }
    else         { f = pi - 16; pos = s % V; }
    float inv = exp2f((float)f * -0.8304820237218407f);
    float ang = (float)pos * inv;
    float cs = __cosf(ang), sn = __sinf(ang);
    size_t base = (size_t)r * HD + pi * 2;
    float xe = (float)X[base];
    float xo = (float)X[base + 1];
    X[base]     = (bf16_t)((xe * cs - xo * sn) * outscale);
    X[base + 1] = (bf16_t)((xe * sn + xo * cs) * outscale);
}

// ---------------- Flash attention (r4 known-good) ----------------
// 256 threads = 4 waves; wave-pair p handles kv half. 64 q/wave.
// No max-subtraction softmax (exp2 domain, scale folded into Q).
__global__ __launch_bounds__(256, 2) void flash_attn(const bf16_t* __restrict__ Q,
                                                     const bf16_t* __restrict__ K,
                                                     const bf16_t* __restrict__ V,
                                                     bf16_t* __restrict__ Y) {
    __shared__ __align__(16) unsigned char smem[65536];
    uint4* Kl = (uint4*)smem;                    // [pair][buf][64*8] uint4  (32 KB)
    uint32_t* Vt = (uint32_t*)(smem + 32768);    // [pair][buf][64*32] dword (32 KB)

    const int t = threadIdx.x;
    const int lane = t & 63;
    const int c = lane & 15, quad = lane >> 4;
    const int wid = t >> 6;            // 0..3
    const int pr = wid >> 1;           // kv pair 0/1
    const int bh = blockIdx.y;
    const int qw = blockIdx.x * 128 + (wid & 1) * 64;

    size_t base = (size_t)bh * SEQ * HD;
    const bf16_t* Qp = Q + base;
    const bf16_t* Vp = V + base + (size_t)pr * 2048 * HD;
    const uint4* Kg = (const uint4*)(K + base) + (size_t)pr * 2048 * 8;

    uint4* Klp = Kl + pr * 1024;
    uint32_t* Vtp = Vt + pr * 4096;

    bf16x8 qf[4][2];
#pragma unroll
    for (int qt = 0; qt < 4; qt++)
#pragma unroll
        for (int ks = 0; ks < 2; ks++)
            qf[qt][ks] = ld8(Qp + (size_t)(qw + qt * 16 + c) * HD + ks * 32 + quad * 8);

    f32x4 acc[4][4];
#pragma unroll
    for (int qt = 0; qt < 4; qt++)
#pragma unroll
        for (int dt = 0; dt < 4; dt++) acc[qt][dt] = f32x4{0.f, 0.f, 0.f, 0.f};
    float lsum[4] = {0.f, 0.f, 0.f, 0.f};

    const int tp = t & 127;
    const int krow = tp >> 3;
    const int kblk = tp & 7;
    const int kva = 2 * (tp & 31);
    const int dc = 16 * (tp >> 5);

    uint4 kreg[4];
    bf16x8 vr0, vr1, vr2, vr3;
#pragma unroll
    for (int i = 0; i < 4; i++) kreg[i] = Kg[(size_t)(i * 16 + krow) * 8 + kblk];
    vr0 = ld8(Vp + (size_t)kva * HD + dc);
    vr1 = ld8(Vp + (size_t)(kva + 1) * HD + dc);
    vr2 = ld8(Vp + (size_t)kva * HD + dc + 8);
    vr3 = ld8(Vp + (size_t)(kva + 1) * HD + dc + 8);

    for (int kt = 0; kt < 32; kt++) {
        uint4* kl = Klp + (kt & 1) * 512;
        uint32_t* vt = Vtp + (kt & 1) * 2048;

#pragma unroll
        for (int i = 0; i < 4; i++) {
            int kv = i * 16 + krow;
            int sk = (kv & 3) | (((kv >> 3) & 1) << 2);
            kl[kv * 8 + (kblk ^ sk)] = kreg[i];
        }
#pragma unroll
        for (int j = 0; j < 8; j++) {
            int d0 = dc + j;
            int sv0 = (d0 & 7) ^ ((d0 >> 3) & 7);
            vt[d0 * 32 + (((kva >> 3) ^ sv0) & 7) * 4 + ((kva & 6) >> 1)] = pack2(vr0[j], vr1[j]);
            int d1 = dc + 8 + j;
            int sv1 = (d1 & 7) ^ ((d1 >> 3) & 7);
            vt[d1 * 32 + (((kva >> 3) ^ sv1) & 7) * 4 + ((kva & 6) >> 1)] = pack2(vr2[j], vr3[j]);
        }

        __syncthreads();

        if (kt + 1 < 32) {
            int kv0n = (kt + 1) * 64;
#pragma unroll
            for (int i = 0; i < 4; i++) kreg[i] = Kg[(size_t)(kv0n + i * 16 + krow) * 8 + kblk];
            vr0 = ld8(Vp + (size_t)(kv0n + kva) * HD + dc);
            vr1 = ld8(Vp + (size_t)(kv0n + kva + 1) * HD + dc);
            vr2 = ld8(Vp + (size_t)(kv0n + kva) * HD + dc + 8);
            vr3 = ld8(Vp + (size_t)(kv0n + kva + 1) * HD + dc + 8);
        }

        f32x4 st[4][4];
#pragma unroll
        for (int n = 0; n < 4; n++) {
            int kvr = (n >> 1) * 32 + ((c >> 2) * 8) + ((n & 1) * 4) + (c & 3);
            int sk = (kvr & 3) | (((kvr >> 3) & 1) << 2);
            bf16x8 k0 = *reinterpret_cast<const bf16x8*>(&kl[kvr * 8 + (quad ^ sk)]);
            bf16x8 k1 = *reinterpret_cast<const bf16x8*>(&kl[kvr * 8 + ((4 + quad) ^ sk)]);
#pragma unroll
            for (int qt = 0; qt < 4; qt++) {
                f32x4 z = f32x4{0.f, 0.f, 0.f, 0.f};
                z = mfma16(k0, qf[qt][0], z);
                z = mfma16(k1, qf[qt][1], z);
                st[qt][n] = z;
            }
        }

        bf16x8 pf[4][2];
#pragma unroll
        for (int qt = 0; qt < 4; qt++) {
            float e[4][4];
            float ls = 0.f;
#pragma unroll
            for (int n = 0; n < 4; n++)
#pragma unroll
                for (int r = 0; r < 4; r++) {
                    float v = __builtin_amdgcn_exp2f(st[qt][n][r]);
                    e[n][r] = v;
                    ls += v;
                }
            lsum[qt] += ls;
            bf16x8 f0, f1;
#pragma unroll
            for (int j = 0; j < 8; j++) {
                f0[j] = (bf16_t)e[(j >> 2)][j & 3];
                f1[j] = (bf16_t)e[2 + (j >> 2)][j & 3];
            }
            pf[qt][0] = f0;
            pf[qt][1] = f1;
        }

#pragma unroll
        for (int dt = 0; dt < 4; dt++) {
            int d = dt * 16 + c;
            int sv = (d & 7) ^ ((d >> 3) & 7);
            bf16x8 v0f = *reinterpret_cast<const bf16x8*>(&vt[d * 32 + ((quad ^ sv) & 7) * 4]);
            bf16x8 v1f = *reinterpret_cast<const bf16x8*>(&vt[d * 32 + (((4 + quad) ^ sv) & 7) * 4]);
#pragma unroll
            for (int qt = 0; qt < 4; qt++) {
                acc[qt][dt] = mfma16(v0f, pf[qt][0], acc[qt][dt]);
                acc[qt][dt] = mfma16(v1f, pf[qt][1], acc[qt][dt]);
            }
        }
    }

    float lred[4];
#pragma unroll
    for (int qt = 0; qt < 4; qt++) {
        float lt = lsum[qt];
        lt += __shfl_xor(lt, 16, 64);
        lt += __shfl_xor(lt, 32, 64);
        lred[qt] = lt;
    }

    __syncthreads();
    float* Ox = (float*)smem;
    float* Lx = (float*)(smem + 128 * 68 * 4);

    if (pr == 1) {
#pragma unroll
        for (int qt = 0; qt < 4; qt++) {
            int ql = (wid & 1) * 64 + qt * 16 + c;
#pragma unroll
            for (int dt = 0; dt < 4; dt++)
                *reinterpret_cast<f32x4*>(&Ox[ql * 68 + dt * 16 + quad * 4]) = acc[qt][dt];
            if (quad == 0) Lx[ql] = lred[qt];
        }
    }
    __syncthreads();
    if (pr == 0) {
        int b_ = bh >> 3, h = bh & 7;
#pragma unroll
        for (int qt = 0; qt < 4; qt++) {
            int ql = (wid & 1) * 64 + qt * 16 + c;
            float inv_l = 1.0f / (lred[qt] + Lx[ql]);
            int srow = qw + qt * 16 + c;
            bf16_t* yrow = Y + (size_t)(b_ * SEQ + srow) * DMODEL + h * HD;
#pragma unroll
            for (int dt = 0; dt < 4; dt++) {
                f32x4 o4 = acc[qt][dt] + *reinterpret_cast<const f32x4*>(&Ox[ql * 68 + dt * 16 + quad * 4]);
                bf16x4 o;
#pragma unroll
                for (int r = 0; r < 4; r++) o[r] = (bf16_t)(o4[r] * inv_l);
                *reinterpret_cast<bf16x4*>(yrow + dt * 16 + quad * 4) = o;
            }
        }
    }
}

extern "C" void kernel_launch(void* const* d_in, const int* in_sizes, int n_in,
                              void* d_out, int out_size, void* d_ws, size_t ws_size,
                              hipStream_t stream) {
    (void)in_sizes; (void)n_in; (void)out_size; (void)ws_size;
    const float* x  = (const float*)d_in[0];
    const float* Wq = (const float*)d_in[1];
    const float* Wk = (const float*)d_in[2];
    const float* Wv = (const float*)d_in[3];
    const float* Wo = (const float*)d_in[4];
    const int*   Vp = (const int*)d_in[6];
    float* out = (float*)d_out;

    bf16_t* ws  = (bf16_t*)d_ws;
    bf16_t* Xb  = ws;                    // 8192*512
    bf16_t* Wc  = Xb  + 4194304;         // [Wq|Wk|Wv]
    bf16_t* Wob = Wc  + 786432;          // 512*512
    bf16_t* Qb  = Wob + 262144;
    bf16_t* Kb  = Qb  + 4194304;
    bf16_t* Vb  = Kb  + 4194304;
    bf16_t* Yb  = Vb  + 4194304;

    cast_all<<<5120, 256, 0, stream>>>(x, Wq, Wk, Wv, Wo, Xb, Wc, Wob);

    gemm_qkv<<<dim3(64, 12), 256, 0, stream>>>(Xb, Wc, Qb, Kb, Vb);

    rope2<<<16384, 256, 0, stream>>>(Qb, Kb, Vp);

    flash_attn<<<dim3(32, 16), 256, 0, stream>>>(Qb, Kb, Vb, Yb);

    gemm_out<<<dim3(64, 4), 256, 0, stream>>>(Yb, Wob, out);
}